// Round 16
// baseline (128.988 us; speedup 1.0000x reference)
//
#include <hip/hip_runtime.h>
#include <hip/hip_bf16.h>

#define NROWS 50000
#define MOBS  2048
#define EDIM  512
#define ODIM  256
#define BM2   128
#define NT2   391               // ceil(50000/128)

typedef short s16x8 __attribute__((ext_vector_type(8)));
typedef float f32x4 __attribute__((ext_vector_type(4)));

typedef const __attribute__((address_space(1))) unsigned int* gptr_t;
typedef __attribute__((address_space(3))) unsigned int* lptr_t;

__device__ __forceinline__ unsigned short f32_to_bf16(float f) {
    unsigned int u = __float_as_uint(f);
    u += 0x7fffu + ((u >> 16) & 1u);     // RNE
    return (unsigned short)(u >> 16);
}

__device__ __forceinline__ s16x8 pack8(f32x4 a, f32x4 b) {
    unsigned int p0, p1, p2, p3;
    asm("v_cvt_pk_bf16_f32 %0, %1, %2" : "=v"(p0) : "v"(a[0]), "v"(a[1]));
    asm("v_cvt_pk_bf16_f32 %0, %1, %2" : "=v"(p1) : "v"(a[2]), "v"(a[3]));
    asm("v_cvt_pk_bf16_f32 %0, %1, %2" : "=v"(p2) : "v"(b[0]), "v"(b[1]));
    asm("v_cvt_pk_bf16_f32 %0, %1, %2" : "=v"(p3) : "v"(b[2]), "v"(b[3]));
    union { unsigned int u[4]; s16x8 v; } r;
    r.u[0] = p0; r.u[1] = p1; r.u[2] = p2; r.u[3] = p3;
    return r.v;
}

// ---------------------------------------------------------------------------
// Pipelined small GEMM: 64x64 tile, 256 thr, 4x4 micro, K-chunk 32,
// register double-buffered staging. ZA/ZB: number of A/B partials summed
// during staging (strides zsA/zsB). NC: K/32 chunks. FRAG: kk-major bf16+I.
// ---------------------------------------------------------------------------
template <int AKM, int BKM, int ZA, int ZB, int NC, int FRAG>
__device__ __forceinline__ void gemm64(const float* __restrict__ A, int lda, size_t zsA,
                                       const float* __restrict__ B, int ldb, size_t zsB,
                                       void* __restrict__ Cv, int ldc,
                                       int i0, int j0, int kbase,
                                       float (*SA)[68], float (*SB)[68]) {
    const int t  = threadIdx.x;
    const int tx = t & 15, ty = t >> 4;

    float4 ra[2][2], rb[2][2];

    auto loadA = [&](float4 (&dst)[2], int c) {
#pragma unroll
        for (int r = 0; r < 2; ++r) {
            int fi = t + r * 256;
            if (AKM) {
                int k = fi >> 4, m4 = (fi & 15) * 4;
                dst[r] = *(const float4*)&A[(size_t)(kbase + c * 32 + k) * lda + i0 + m4];
            } else {
                int i = fi >> 3, kq = (fi & 7) * 4;
                const float* p = &A[(size_t)(i0 + i) * lda + kbase + c * 32 + kq];
                float4 v = *(const float4*)p;
#pragma unroll
                for (int z = 1; z < ZA; ++z) {
                    float4 w2 = *(const float4*)(p + z * zsA);
                    v.x += w2.x; v.y += w2.y; v.z += w2.z; v.w += w2.w;
                }
                dst[r] = v;
            }
        }
    };
    auto loadB = [&](float4 (&dst)[2], int c) {
#pragma unroll
        for (int r = 0; r < 2; ++r) {
            int fi = t + r * 256;
            if (BKM) {
                int k = fi >> 4, j4 = (fi & 15) * 4;
                const float* p = &B[(size_t)(kbase + c * 32 + k) * ldb + j0 + j4];
                float4 v = *(const float4*)p;
#pragma unroll
                for (int z = 1; z < ZB; ++z) {
                    float4 w2 = *(const float4*)(p + z * zsB);
                    v.x += w2.x; v.y += w2.y; v.z += w2.z; v.w += w2.w;
                }
                dst[r] = v;
            } else {
                int j = fi >> 3, kq = (fi & 7) * 4;
                dst[r] = *(const float4*)&B[(size_t)(j0 + j) * ldb + kbase + c * 32 + kq];
            }
        }
    };
    auto storeA = [&](float4 (&src)[2]) {
#pragma unroll
        for (int r = 0; r < 2; ++r) {
            int fi = t + r * 256;
            if (AKM) {
                int k = fi >> 4, m4 = (fi & 15) * 4;
                *(float4*)&SA[k][m4] = src[r];
            } else {
                int i = fi >> 3, kq = (fi & 7) * 4;
                float4 v = src[r];
                SA[kq][i] = v.x; SA[kq + 1][i] = v.y;
                SA[kq + 2][i] = v.z; SA[kq + 3][i] = v.w;
            }
        }
    };
    auto storeB = [&](float4 (&src)[2]) {
#pragma unroll
        for (int r = 0; r < 2; ++r) {
            int fi = t + r * 256;
            if (BKM) {
                int k = fi >> 4, j4 = (fi & 15) * 4;
                *(float4*)&SB[k][j4] = src[r];
            } else {
                int j = fi >> 3, kq = (fi & 7) * 4;
                float4 v = src[r];
                SB[kq][j] = v.x; SB[kq + 1][j] = v.y;
                SB[kq + 2][j] = v.z; SB[kq + 3][j] = v.w;
            }
        }
    };

    float acc[4][4];
#pragma unroll
    for (int a = 0; a < 4; ++a)
#pragma unroll
        for (int b2 = 0; b2 < 4; ++b2) acc[a][b2] = 0.f;

    loadA(ra[0], 0);
    loadB(rb[0], 0);

#pragma unroll
    for (int c = 0; c < NC; ++c) {
        const int cur = c & 1, nxt = cur ^ 1;
        if (c + 1 < NC) {
            loadA(ra[nxt], c + 1);
            loadB(rb[nxt], c + 1);
        }
        storeA(ra[cur]);
        storeB(rb[cur]);
        __syncthreads();
#pragma unroll
        for (int kk = 0; kk < 32; ++kk) {
            float4 a4 = *(const float4*)&SA[kk][ty * 4];
            float4 b4 = *(const float4*)&SB[kk][tx * 4];
            float av[4] = {a4.x, a4.y, a4.z, a4.w};
            float bv[4] = {b4.x, b4.y, b4.z, b4.w};
#pragma unroll
            for (int a = 0; a < 4; ++a)
#pragma unroll
                for (int b2 = 0; b2 < 4; ++b2) acc[a][b2] += av[a] * bv[b2];
        }
        __syncthreads();
    }

    if (FRAG) {
        unsigned short* C = (unsigned short*)Cv;
#pragma unroll
        for (int a = 0; a < 4; ++a)
#pragma unroll
            for (int b2 = 0; b2 < 4; ++b2) {
                int i = i0 + ty * 4 + a;
                int j = j0 + tx * 4 + b2;
                float v = acc[a][b2] + (i == j ? 1.f : 0.f);
                size_t idx = ((size_t)(((i >> 5) * 32 + (j >> 4)) * 64
                               + ((i >> 3) & 3) * 16 + (j & 15))) * 8 + (i & 7);
                C[idx] = f32_to_bf16(v);
            }
    } else {
        float* C = (float*)Cv;
#pragma unroll
        for (int a = 0; a < 4; ++a) {
            float4 o = make_float4(acc[a][0], acc[a][1], acc[a][2], acc[a][3]);
            *(float4*)&C[(size_t)(i0 + ty * 4 + a) * ldc + j0 + tx * 4] = o;
        }
    }
}

// Chain D1 (512 blocks): b<256: Gp[z] = obs-chunk^T @ obs-chunk, z=b>>4
// (16 partials, K=128 each, NC=4).  b>=256: Pp[z] = Wq^T@Wk chunk, z 8
// partials x 32 tiles, K=64, NC=2.
__global__ __launch_bounds__(256) void chain1(const float* __restrict__ obs,
                                              const float* __restrict__ Wq,
                                              const float* __restrict__ Wk,
                                              float* __restrict__ Gp,
                                              float* __restrict__ Pp) {
    __shared__ float SA[32][68];
    __shared__ float SB[32][68];
    const int b = blockIdx.x;
    if (b < 256) {
        int z = b >> 4, tile = b & 15;
        gemm64<1, 1, 1, 1, 4, 0>(obs, ODIM, 0, obs, ODIM, 0,
                                 Gp + (size_t)z * 65536, ODIM,
                                 (tile >> 2) * 64, (tile & 3) * 64, z * 128, SA, SB);
    } else {
        int i2 = b - 256;
        int z = i2 >> 5, tile = i2 & 31;
        gemm64<1, 1, 1, 1, 2, 0>(Wq, EDIM, 0, Wk, ODIM, 0,
                                 Pp + (size_t)z * 131072, ODIM,
                                 (tile >> 2) * 64, (tile & 3) * 64, z * 64, SA, SB);
    }
}

// Chain D2 (64 blocks): GWp[z] = (sum_16 Gp) @ Wv^T, split-K 2 (z=bz),
// K=128 each, NC=4.  grid(8,4,2).
__global__ __launch_bounds__(256) void chain2(const float* __restrict__ Gp,
                                              const float* __restrict__ Wv,
                                              float* __restrict__ GWp) {
    __shared__ float SA[32][68];
    __shared__ float SB[32][68];
    const int z = blockIdx.z;
    gemm64<0, 0, 16, 1, 4, 0>(Gp, ODIM, 65536, Wv, ODIM, 0,
                              GWp + (size_t)z * 131072, EDIM,
                              blockIdx.y * 64, blockIdx.x * 64, z * 128, SA, SB);
}

// Chain D3 (64 blocks): Uf = frag_kkmajor((sum_8 Pp) @ (sum_2 GWp) + I),
// K=256, NC=8.  grid(8,8).
__global__ __launch_bounds__(256) void chain3(const float* __restrict__ Pp,
                                              const float* __restrict__ GWp,
                                              unsigned short* __restrict__ Uf) {
    __shared__ float SA[32][68];
    __shared__ float SB[32][68];
    gemm64<0, 1, 8, 2, 8, 1>(Pp, ODIM, 131072, GWp, EDIM, 131072,
                             (void*)Uf, EDIM,
                             blockIdx.y * 64, blockIdx.x * 64, 0, SA, SB);
}

// ---------------------------------------------------------------------------
// Main: out = LayerNorm(node @ (U+I)).  (R14/R11 exact — measured best ~73us)
// 3-deep DMA pipeline, counted vmcnt. Tile 128x512, BK=32, 16 K-steps.
// ---------------------------------------------------------------------------
__global__ __launch_bounds__(512, 2) void gemm_pipe_ln(
    const float* __restrict__ node, const unsigned short* __restrict__ Uf,
    const float* __restrict__ gamma, const float* __restrict__ beta,
    float* __restrict__ out) {
    __shared__ char smem[147456];           // A: [3][16KB] | B: [3][32KB]
    char* Areg = smem;
    char* Breg = smem + 49152;
    float* lds_s  = (float*)smem;           // stats alias (A dead after loop)
    float* lds_q  = (float*)smem + 512;
    float* lds_mu = (float*)smem + 1024;
    float* lds_rs = (float*)smem + 1152;

    const int t  = threadIdx.x;
    const int w  = t >> 6, l = t & 63;
    const int rg = w >> 2, cg = w & 3;
    const int lr = l & 15, lk = l >> 4;
    const int m0 = blockIdx.x * BM2;

    const int sr = w * 8 + (l >> 3);
    const int schunk = (l & 7) ^ ((l >> 3) & 7);
    int gr0 = m0 + sr;      if (gr0 > NROWS - 1) gr0 = NROWS - 1;
    int gr1 = m0 + sr + 64; if (gr1 > NROWS - 1) gr1 = NROWS - 1;
    const char* asrc0 = (const char*)node + (size_t)gr0 * 2048 + schunk * 16;
    const char* asrc1 = (const char*)node + (size_t)gr1 * 2048 + schunk * 16;
    const char* bsrc  = (const char*)Uf + (size_t)w * 4096 + (size_t)l * 16;

    auto dma = [&](int buf, int kt) {
        char* ad = Areg + buf * 16384 + w * 1024;
        __builtin_amdgcn_global_load_lds((gptr_t)(asrc0 + kt * 128),
                                         (lptr_t)ad, 16, 0, 0);
        __builtin_amdgcn_global_load_lds((gptr_t)(asrc1 + kt * 128),
                                         (lptr_t)(ad + 8192), 16, 0, 0);
        char* bd = Breg + buf * 32768 + w * 4096;
        const char* bs = bsrc + (size_t)kt * 32768;
#pragma unroll
        for (int j = 0; j < 4; ++j)
            __builtin_amdgcn_global_load_lds((gptr_t)(bs + j * 1024),
                                             (lptr_t)(bd + j * 1024), 16, 0, 0);
    };

    f32x4 acc[4][8];
#pragma unroll
    for (int mi = 0; mi < 4; ++mi)
#pragma unroll
        for (int ni = 0; ni < 8; ++ni)
            acc[mi][ni] = (f32x4){0.f, 0.f, 0.f, 0.f};

    auto compute = [&](int cur) {
        const char* bbase = Breg + cur * 32768 + cg * 8192 + l * 16;
        s16x8 bfr[8];
#pragma unroll
        for (int ni = 0; ni < 8; ++ni)
            bfr[ni] = *(const s16x8*)(bbase + ni * 1024);
        s16x8 afr[4];
#pragma unroll
        for (int mi = 0; mi < 4; ++mi) {
            int row = rg * 64 + mi * 16 + lr;          // row&7 == lr&7
            const char* rb = Areg + cur * 16384 + row * 128;
            f32x4 a0 = *(const f32x4*)(rb + ((2 * lk)     ^ (lr & 7)) * 16);
            f32x4 a1 = *(const f32x4*)(rb + ((2 * lk + 1) ^ (lr & 7)) * 16);
            afr[mi] = pack8(a0, a1);
        }
#pragma unroll
        for (int mi = 0; mi < 4; ++mi)
#pragma unroll
            for (int ni = 0; ni < 8; ++ni)
                acc[mi][ni] = __builtin_amdgcn_mfma_f32_16x16x32_bf16(
                    afr[mi], bfr[ni], acc[mi][ni], 0, 0, 0);
    };

    dma(0, 0);
    dma(1, 1);

#pragma unroll 1
    for (int kt = 0; kt < 14; ++kt) {
        dma((kt + 2) % 3, kt + 2);
        asm volatile("s_waitcnt vmcnt(12)" ::: "memory");
        __builtin_amdgcn_sched_barrier(0);
        __builtin_amdgcn_s_barrier();
        compute(kt % 3);
        __builtin_amdgcn_s_barrier();
    }
    asm volatile("s_waitcnt vmcnt(6)" ::: "memory");
    __builtin_amdgcn_sched_barrier(0);
    __builtin_amdgcn_s_barrier();
    compute(14 % 3);
    __builtin_amdgcn_s_barrier();
    asm volatile("s_waitcnt vmcnt(0)" ::: "memory");
    __builtin_amdgcn_sched_barrier(0);
    __builtin_amdgcn_s_barrier();
    compute(15 % 3);
    __syncthreads();                   // reads done before stats aliasing

    // ---- LN stats ----
#pragma unroll
    for (int mi = 0; mi < 4; ++mi) {
#pragma unroll
        for (int j = 0; j < 4; ++j) {
            float sm = 0.f, q = 0.f;
#pragma unroll
            for (int ni = 0; ni < 8; ++ni) {
                float v = acc[mi][ni][j];
                sm += v; q += v * v;
            }
#pragma unroll
            for (int off = 1; off < 16; off <<= 1) {
                sm += __shfl_xor(sm, off);
                q  += __shfl_xor(q, off);
            }
            if (lr == 0) {
                int row = rg * 64 + mi * 16 + lk * 4 + j;
                lds_s[cg * 128 + row] = sm;
                lds_q[cg * 128 + row] = q;
            }
        }
    }
    __syncthreads();
    if (t < 128) {
        float sm = lds_s[t] + lds_s[128 + t] + lds_s[256 + t] + lds_s[384 + t];
        float q  = lds_q[t] + lds_q[128 + t] + lds_q[256 + t] + lds_q[384 + t];
        float mu  = sm * (1.f / (float)EDIM);
        float var = q * (1.f / (float)EDIM) - mu * mu;
        lds_mu[t] = mu;
        lds_rs[t] = rsqrtf(var + 1e-6f);
    }
    __syncthreads();

    float gv[8], bv[8];
#pragma unroll
    for (int ni = 0; ni < 8; ++ni) {
        int col = cg * 128 + ni * 16 + lr;
        gv[ni] = gamma[col];
        bv[ni] = beta[col];
    }

#pragma unroll
    for (int mi = 0; mi < 4; ++mi) {
#pragma unroll
        for (int j = 0; j < 4; ++j) {
            int row = rg * 64 + mi * 16 + lk * 4 + j;
            int gr = m0 + row;
            if (gr < NROWS) {
                float mu = lds_mu[row], rs = lds_rs[row];
                float* op = out + (size_t)gr * EDIM + cg * 128 + lr;
#pragma unroll
                for (int ni = 0; ni < 8; ++ni)
                    op[ni * 16] = (acc[mi][ni][j] - mu) * rs * gv[ni] + bv[ni];
            }
        }
    }
}

// ---------------------------------------------------------------------------
extern "C" void kernel_launch(void* const* d_in, const int* in_sizes, int n_in,
                              void* d_out, int out_size, void* d_ws, size_t ws_size,
                              hipStream_t stream) {
    const float* node  = (const float*)d_in[0];   // [N, E]
    const float* obs   = (const float*)d_in[1];   // [M, O]
    const float* Wq    = (const float*)d_in[2];   // [E, E]
    const float* Wk    = (const float*)d_in[3];   // [E, O]
    const float* Wv    = (const float*)d_in[4];   // [E, O]
    const float* gamma = (const float*)d_in[5];   // [E]
    const float* beta  = (const float*)d_in[6];   // [E]
    float* out = (float*)d_out;

    // ws: Gp [16][256x256] (4MB) | Pp [8][512x256] (4MB) | GWp [2][256x512]
    //   (1MB) | Uf kk-major frag bf16 (512KB)
    float* ws = (float*)d_ws;
    float* Gp  = ws;
    float* Pp  = Gp + 16 * 65536;
    float* GWp = Pp + 8 * 131072;
    unsigned short* Uf = (unsigned short*)(GWp + 2 * 131072);

    // D1: G-partials (256 blk, NC=4) + P-partials (256 blk, NC=2)
    chain1<<<dim3(512), 256, 0, stream>>>(obs, Wq, Wk, Gp, Pp);
    // D2: GWp[2] = (sum_16 Gp) @ Wv^T partials, split-K 2
    chain2<<<dim3(8, 4, 2), 256, 0, stream>>>(Gp, Wv, GWp);
    // D3: Uf = frag((sum_8 Pp) @ (sum_2 GWp) + I), kk-major frag
    chain3<<<dim3(8, 8), 256, 0, stream>>>(Pp, GWp, Uf);
    // D4: out = LN(node @ (U+I)), BM=128, 3-deep counted-vmcnt pipeline
    gemm_pipe_ln<<<dim3(NT2), 512, 0, stream>>>(node, Uf, gamma, beta, out);
}

// Round 17
// 115.356 us; speedup vs baseline: 1.1182x; 1.1182x over previous
//
#include <hip/hip_runtime.h>
#include <hip/hip_bf16.h>

#define NROWS 50000
#define MOBS  2048
#define EDIM  512
#define ODIM  256
#define BM2   128
#define NT2   391               // ceil(50000/128)

typedef short s16x8 __attribute__((ext_vector_type(8)));
typedef float f32x4 __attribute__((ext_vector_type(4)));

typedef const __attribute__((address_space(1))) unsigned int* gptr_t;
typedef __attribute__((address_space(3))) unsigned int* lptr_t;

__device__ __forceinline__ unsigned short f32_to_bf16(float f) {
    unsigned int u = __float_as_uint(f);
    u += 0x7fffu + ((u >> 16) & 1u);     // RNE
    return (unsigned short)(u >> 16);
}

__device__ __forceinline__ s16x8 pack8(f32x4 a, f32x4 b) {
    unsigned int p0, p1, p2, p3;
    asm("v_cvt_pk_bf16_f32 %0, %1, %2" : "=v"(p0) : "v"(a[0]), "v"(a[1]));
    asm("v_cvt_pk_bf16_f32 %0, %1, %2" : "=v"(p1) : "v"(a[2]), "v"(a[3]));
    asm("v_cvt_pk_bf16_f32 %0, %1, %2" : "=v"(p2) : "v"(b[0]), "v"(b[1]));
    asm("v_cvt_pk_bf16_f32 %0, %1, %2" : "=v"(p3) : "v"(b[2]), "v"(b[3]));
    union { unsigned int u[4]; s16x8 v; } r;
    r.u[0] = p0; r.u[1] = p1; r.u[2] = p2; r.u[3] = p3;
    return r.v;
}

// ---------------------------------------------------------------------------
// Pipelined small GEMM (R14 verbatim): 64x64 tile, 256 thr, 4x4 micro,
// K-chunk 32, register double-buffered staging (loads for chunk c+1 issued
// before LDS-write + compute of chunk c).
//  AKM=1: A k-major A[k*lda+i]   AKM=0: A i-major A[i*lda+k] (+ZA-sum)
//  BKM=1: B k-major B[k*ldb+j]   BKM=0: B j-major B[j*ldb+k]
//  FRAG=1: kk-major frag-bf16 output +I (for main DMA); else plain f32.
// ---------------------------------------------------------------------------
template <int AKM, int BKM, int ZA, int NC, int FRAG>
__device__ __forceinline__ void gemm64(const float* __restrict__ A, int lda, size_t zsA,
                                       const float* __restrict__ B, int ldb,
                                       void* __restrict__ Cv, int ldc,
                                       int i0, int j0, int kbase,
                                       float (*SA)[68], float (*SB)[68]) {
    const int t  = threadIdx.x;
    const int tx = t & 15, ty = t >> 4;

    float4 ra[2][2], rb[2][2];

    auto loadA = [&](float4 (&dst)[2], int c) {
#pragma unroll
        for (int r = 0; r < 2; ++r) {
            int fi = t + r * 256;
            if (AKM) {
                int k = fi >> 4, m4 = (fi & 15) * 4;
                dst[r] = *(const float4*)&A[(size_t)(kbase + c * 32 + k) * lda + i0 + m4];
            } else {
                int i = fi >> 3, kq = (fi & 7) * 4;
                const float* p = &A[(size_t)(i0 + i) * lda + kbase + c * 32 + kq];
                float4 v = *(const float4*)p;
#pragma unroll
                for (int z = 1; z < ZA; ++z) {
                    float4 w2 = *(const float4*)(p + z * zsA);
                    v.x += w2.x; v.y += w2.y; v.z += w2.z; v.w += w2.w;
                }
                dst[r] = v;
            }
        }
    };
    auto loadB = [&](float4 (&dst)[2], int c) {
#pragma unroll
        for (int r = 0; r < 2; ++r) {
            int fi = t + r * 256;
            if (BKM) {
                int k = fi >> 4, j4 = (fi & 15) * 4;
                dst[r] = *(const float4*)&B[(size_t)(kbase + c * 32 + k) * ldb + j0 + j4];
            } else {
                int j = fi >> 3, kq = (fi & 7) * 4;
                dst[r] = *(const float4*)&B[(size_t)(j0 + j) * ldb + kbase + c * 32 + kq];
            }
        }
    };
    auto storeA = [&](float4 (&src)[2]) {
#pragma unroll
        for (int r = 0; r < 2; ++r) {
            int fi = t + r * 256;
            if (AKM) {
                int k = fi >> 4, m4 = (fi & 15) * 4;
                *(float4*)&SA[k][m4] = src[r];
            } else {
                int i = fi >> 3, kq = (fi & 7) * 4;
                float4 v = src[r];
                SA[kq][i] = v.x; SA[kq + 1][i] = v.y;
                SA[kq + 2][i] = v.z; SA[kq + 3][i] = v.w;
            }
        }
    };
    auto storeB = [&](float4 (&src)[2]) {
#pragma unroll
        for (int r = 0; r < 2; ++r) {
            int fi = t + r * 256;
            if (BKM) {
                int k = fi >> 4, j4 = (fi & 15) * 4;
                *(float4*)&SB[k][j4] = src[r];
            } else {
                int j = fi >> 3, kq = (fi & 7) * 4;
                float4 v = src[r];
                SB[kq][j] = v.x; SB[kq + 1][j] = v.y;
                SB[kq + 2][j] = v.z; SB[kq + 3][j] = v.w;
            }
        }
    };

    float acc[4][4];
#pragma unroll
    for (int a = 0; a < 4; ++a)
#pragma unroll
        for (int b2 = 0; b2 < 4; ++b2) acc[a][b2] = 0.f;

    loadA(ra[0], 0);
    loadB(rb[0], 0);

#pragma unroll
    for (int c = 0; c < NC; ++c) {
        const int cur = c & 1, nxt = cur ^ 1;
        if (c + 1 < NC) {
            loadA(ra[nxt], c + 1);
            loadB(rb[nxt], c + 1);
        }
        storeA(ra[cur]);
        storeB(rb[cur]);
        __syncthreads();
#pragma unroll
        for (int kk = 0; kk < 32; ++kk) {
            float4 a4 = *(const float4*)&SA[kk][ty * 4];
            float4 b4 = *(const float4*)&SB[kk][tx * 4];
            float av[4] = {a4.x, a4.y, a4.z, a4.w};
            float bv[4] = {b4.x, b4.y, b4.z, b4.w};
#pragma unroll
            for (int a = 0; a < 4; ++a)
#pragma unroll
                for (int b2 = 0; b2 < 4; ++b2) acc[a][b2] += av[a] * bv[b2];
        }
        __syncthreads();
    }

    if (FRAG) {
        unsigned short* C = (unsigned short*)Cv;
#pragma unroll
        for (int a = 0; a < 4; ++a)
#pragma unroll
            for (int b2 = 0; b2 < 4; ++b2) {
                int i = i0 + ty * 4 + a;       // k-dim of main GEMM
                int j = j0 + tx * 4 + b2;      // col of main GEMM
                float v = acc[a][b2] + (i == j ? 1.f : 0.f);
                size_t idx = ((size_t)(((i >> 5) * 32 + (j >> 4)) * 64
                               + ((i >> 3) & 3) * 16 + (j & 15))) * 8 + (i & 7);
                C[idx] = f32_to_bf16(v);
            }
    } else {
        float* C = (float*)Cv;
#pragma unroll
        for (int a = 0; a < 4; ++a) {
            float4 o = make_float4(acc[a][0], acc[a][1], acc[a][2], acc[a][3]);
            *(float4*)&C[(size_t)(i0 + ty * 4 + a) * ldc + j0 + tx * 4] = o;
        }
    }
}

// Chain D1 (R14): Gp[z] = obs-chunk^T @ obs-chunk (b<128, z=b>>4, K=256, NC=8)
//                 Pp[z] = Wq-chunk^T @ Wk-chunk   (b>=128, z=(b-128)>>5, K=128, NC=4)
__global__ __launch_bounds__(256) void chain1(const float* __restrict__ obs,
                                              const float* __restrict__ Wq,
                                              const float* __restrict__ Wk,
                                              float* __restrict__ Gp,
                                              float* __restrict__ Pp) {
    __shared__ float SA[32][68];
    __shared__ float SB[32][68];
    const int b = blockIdx.x;
    if (b < 128) {
        int z = b >> 4, tile = b & 15;
        gemm64<1, 1, 1, 8, 0>(obs, ODIM, 0, obs, ODIM,
                              Gp + (size_t)z * 65536, ODIM,
                              (tile >> 2) * 64, (tile & 3) * 64, z * 256, SA, SB);
    } else {
        int i2 = b - 128;
        int z = i2 >> 5, tile = i2 & 31;
        gemm64<1, 1, 1, 4, 0>(Wq, EDIM, 0, Wk, ODIM,
                              Pp + (size_t)z * 131072, ODIM,
                              (tile >> 2) * 64, (tile & 3) * 64, z * 128, SA, SB);
    }
}

// Chain D2 (R14): GW = (sum_8 Gp) @ Wv^T   [256,512] K=256.  grid(8,4).
__global__ __launch_bounds__(256) void chain2(const float* __restrict__ Gp,
                                              const float* __restrict__ Wv,
                                              float* __restrict__ GW) {
    __shared__ float SA[32][68];
    __shared__ float SB[32][68];
    gemm64<0, 0, 8, 8, 0>(Gp, ODIM, 65536, Wv, ODIM, GW, EDIM,
                          blockIdx.y * 64, blockIdx.x * 64, 0, SA, SB);
}

// Chain D3 (R14): Uf = frag_kkmajor((sum_4 Pp) @ GW + I)  [512,512] K=256. grid(8,8).
__global__ __launch_bounds__(256) void chain3(const float* __restrict__ Pp,
                                              const float* __restrict__ GW,
                                              unsigned short* __restrict__ Uf) {
    __shared__ float SA[32][68];
    __shared__ float SB[32][68];
    gemm64<0, 1, 4, 8, 1>(Pp, ODIM, 131072, GW, EDIM, (void*)Uf, EDIM,
                          blockIdx.y * 64, blockIdx.x * 64, 0, SA, SB);
}

// ---------------------------------------------------------------------------
// Main: out = LayerNorm(node @ (U+I)).  (R11/R14 exact — measured best ~72us)
// 3-deep DMA pipeline, counted vmcnt (never drains to 0 in-loop, T4).
// Tile 128x512, BK=32, 16 K-steps. LDS: A 3x16KB + B 3x32KB = 144KB.
// Per iter: issue dma(kt+2) -> s_waitcnt vmcnt(12) -> s_barrier ->
// compute(kt) -> s_barrier.
// ---------------------------------------------------------------------------
__global__ __launch_bounds__(512, 2) void gemm_pipe_ln(
    const float* __restrict__ node, const unsigned short* __restrict__ Uf,
    const float* __restrict__ gamma, const float* __restrict__ beta,
    float* __restrict__ out) {
    __shared__ char smem[147456];           // A: [3][16KB] | B: [3][32KB]
    char* Areg = smem;
    char* Breg = smem + 49152;
    float* lds_s  = (float*)smem;           // stats alias (A dead after loop)
    float* lds_q  = (float*)smem + 512;
    float* lds_mu = (float*)smem + 1024;
    float* lds_rs = (float*)smem + 1152;

    const int t  = threadIdx.x;
    const int w  = t >> 6, l = t & 63;
    const int rg = w >> 2, cg = w & 3;
    const int lr = l & 15, lk = l >> 4;
    const int m0 = blockIdx.x * BM2;

    // DMA source: lane covers (row = w*8 + (l>>3), chunk = l&7), source
    // chunk pre-swizzled (linear LDS dest + inv-swz source, rule #21).
    const int sr = w * 8 + (l >> 3);
    const int schunk = (l & 7) ^ ((l >> 3) & 7);
    int gr0 = m0 + sr;      if (gr0 > NROWS - 1) gr0 = NROWS - 1;
    int gr1 = m0 + sr + 64; if (gr1 > NROWS - 1) gr1 = NROWS - 1;
    const char* asrc0 = (const char*)node + (size_t)gr0 * 2048 + schunk * 16;
    const char* asrc1 = (const char*)node + (size_t)gr1 * 2048 + schunk * 16;
    const char* bsrc  = (const char*)Uf + (size_t)w * 4096 + (size_t)l * 16;

    auto dma = [&](int buf, int kt) {
        char* ad = Areg + buf * 16384 + w * 1024;
        __builtin_amdgcn_global_load_lds((gptr_t)(asrc0 + kt * 128),
                                         (lptr_t)ad, 16, 0, 0);
        __builtin_amdgcn_global_load_lds((gptr_t)(asrc1 + kt * 128),
                                         (lptr_t)(ad + 8192), 16, 0, 0);
        char* bd = Breg + buf * 32768 + w * 4096;
        const char* bs = bsrc + (size_t)kt * 32768;
#pragma unroll
        for (int j = 0; j < 4; ++j)
            __builtin_amdgcn_global_load_lds((gptr_t)(bs + j * 1024),
                                             (lptr_t)(bd + j * 1024), 16, 0, 0);
    };

    f32x4 acc[4][8];
#pragma unroll
    for (int mi = 0; mi < 4; ++mi)
#pragma unroll
        for (int ni = 0; ni < 8; ++ni)
            acc[mi][ni] = (f32x4){0.f, 0.f, 0.f, 0.f};

    auto compute = [&](int cur) {
        const char* bbase = Breg + cur * 32768 + cg * 8192 + l * 16;
        s16x8 bfr[8];
#pragma unroll
        for (int ni = 0; ni < 8; ++ni)
            bfr[ni] = *(const s16x8*)(bbase + ni * 1024);
        s16x8 afr[4];
#pragma unroll
        for (int mi = 0; mi < 4; ++mi) {
            int row = rg * 64 + mi * 16 + lr;          // row&7 == lr&7
            const char* rb = Areg + cur * 16384 + row * 128;
            f32x4 a0 = *(const f32x4*)(rb + ((2 * lk)     ^ (lr & 7)) * 16);
            f32x4 a1 = *(const f32x4*)(rb + ((2 * lk + 1) ^ (lr & 7)) * 16);
            afr[mi] = pack8(a0, a1);
        }
#pragma unroll
        for (int mi = 0; mi < 4; ++mi)
#pragma unroll
            for (int ni = 0; ni < 8; ++ni)
                acc[mi][ni] = __builtin_amdgcn_mfma_f32_16x16x32_bf16(
                    afr[mi], bfr[ni], acc[mi][ni], 0, 0, 0);
    };

    dma(0, 0);
    dma(1, 1);

#pragma unroll 1
    for (int kt = 0; kt < 14; ++kt) {
        dma((kt + 2) % 3, kt + 2);
        asm volatile("s_waitcnt vmcnt(12)" ::: "memory");
        __builtin_amdgcn_sched_barrier(0);
        __builtin_amdgcn_s_barrier();
        compute(kt % 3);
        __builtin_amdgcn_s_barrier();
    }
    // kt = 14
    asm volatile("s_waitcnt vmcnt(6)" ::: "memory");
    __builtin_amdgcn_sched_barrier(0);
    __builtin_amdgcn_s_barrier();
    compute(14 % 3);
    __builtin_amdgcn_s_barrier();
    // kt = 15
    asm volatile("s_waitcnt vmcnt(0)" ::: "memory");
    __builtin_amdgcn_sched_barrier(0);
    __builtin_amdgcn_s_barrier();
    compute(15 % 3);
    __syncthreads();                   // all reads done before stats aliasing

    // ---- LN stats ----
#pragma unroll
    for (int mi = 0; mi < 4; ++mi) {
#pragma unroll
        for (int j = 0; j < 4; ++j) {
            float sm = 0.f, q = 0.f;
#pragma unroll
            for (int ni = 0; ni < 8; ++ni) {
                float v = acc[mi][ni][j];
                sm += v; q += v * v;
            }
#pragma unroll
            for (int off = 1; off < 16; off <<= 1) {
                sm += __shfl_xor(sm, off);
                q  += __shfl_xor(q, off);
            }
            if (lr == 0) {
                int row = rg * 64 + mi * 16 + lk * 4 + j;
                lds_s[cg * 128 + row] = sm;
                lds_q[cg * 128 + row] = q;
            }
        }
    }
    __syncthreads();
    if (t < 128) {
        float sm = lds_s[t] + lds_s[128 + t] + lds_s[256 + t] + lds_s[384 + t];
        float q  = lds_q[t] + lds_q[128 + t] + lds_q[256 + t] + lds_q[384 + t];
        float mu  = sm * (1.f / (float)EDIM);
        float var = q * (1.f / (float)EDIM) - mu * mu;
        lds_mu[t] = mu;
        lds_rs[t] = rsqrtf(var + 1e-6f);
    }
    __syncthreads();

    float gv[8], bv[8];
#pragma unroll
    for (int ni = 0; ni < 8; ++ni) {
        int col = cg * 128 + ni * 16 + lr;
        gv[ni] = gamma[col];
        bv[ni] = beta[col];
    }

#pragma unroll
    for (int mi = 0; mi < 4; ++mi) {
#pragma unroll
        for (int j = 0; j < 4; ++j) {
            int row = rg * 64 + mi * 16 + lk * 4 + j;
            int gr = m0 + row;
            if (gr < NROWS) {
                float mu = lds_mu[row], rs = lds_rs[row];
                float* op = out + (size_t)gr * EDIM + cg * 128 + lr;
#pragma unroll
                for (int ni = 0; ni < 8; ++ni)
                    op[ni * 16] = (acc[mi][ni][j] - mu) * rs * gv[ni] + bv[ni];
            }
        }
    }
}

// ---------------------------------------------------------------------------
extern "C" void kernel_launch(void* const* d_in, const int* in_sizes, int n_in,
                              void* d_out, int out_size, void* d_ws, size_t ws_size,
                              hipStream_t stream) {
    const float* node  = (const float*)d_in[0];   // [N, E]
    const float* obs   = (const float*)d_in[1];   // [M, O]
    const float* Wq    = (const float*)d_in[2];   // [E, E]
    const float* Wk    = (const float*)d_in[3];   // [E, O]
    const float* Wv    = (const float*)d_in[4];   // [E, O]
    const float* gamma = (const float*)d_in[5];   // [E]
    const float* beta  = (const float*)d_in[6];   // [E]
    float* out = (float*)d_out;

    // ws: Gp [8][256x256] (2MB) | Pp [4][512x256] (2MB) | GW [256x512]
    //   | Uf kk-major frag bf16 (512KB)
    float* ws = (float*)d_ws;
    float* Gp = ws;
    float* Pp = Gp + 8 * 65536;
    float* GW = Pp + 4 * 131072;
    unsigned short* Uf = (unsigned short*)(GW + ODIM * EDIM);

    // D1: G-partials (128 blk) + P-partials (128 blk), pure stores, pipelined
    chain1<<<dim3(256), 256, 0, stream>>>(obs, Wq, Wk, Gp, Pp);
    // D2: GW = (sum Gp) @ Wv^T   [256,512] K=256
    chain2<<<dim3(8, 4), 256, 0, stream>>>(Gp, Wv, GW);
    // D3: Uf = frag((sum Pp) @ GW + I)  [512,512] K=256, kk-major frag
    chain3<<<dim3(8, 8), 256, 0, stream>>>(Pp, GW, Uf);
    // D4: out = LN(node @ (U+I)), 3-deep counted-vmcnt pipeline
    gemm_pipe_ln<<<dim3(NT2), 512, 0, stream>>>(node, Uf, gamma, beta, out);
}